// Round 17
// baseline (156.958 us; speedup 1.0000x reference)
//
#include <hip/hip_runtime.h>
#include <hip/hip_bf16.h>

typedef __attribute__((ext_vector_type(8))) short short8;
typedef __attribute__((ext_vector_type(4))) short short4v;
typedef __attribute__((ext_vector_type(4))) float f32x4;

#define LD4(dst, v4) { dst[0]=(v4).x; dst[1]=(v4).y; dst[2]=(v4).z; dst[3]=(v4).w; }

// B=2, T=512, CM=256, CZ=128, H=16, DH=16
static __device__ __forceinline__ short f2bf(float f) {
    union { float f; unsigned u; } v; v.f = f;
    unsigned r = (v.u + 0x7FFFu + ((v.u >> 16) & 1u)) >> 16;
    return (short)r;
}
static __device__ __forceinline__ float bf2f(short s) {
    union { unsigned u; float f; } v; v.u = ((unsigned)(unsigned short)s) << 16;
    return v.f;
}
static __device__ __forceinline__ unsigned cvt_pk_bf16(float lo, float hi) {
    unsigned r;
    asm volatile("v_cvt_pk_bf16_f32 %0, %1, %2" : "=v"(r) : "v"(lo), "v"(hi));
    return r;
}

// ---------------- proj tile (32 rows x 128 cols), R5/R7-proven ----------------
static __device__ __forceinline__ void proj_tile(
    const float* __restrict__ X, const float* __restrict__ W,
    const float* __restrict__ bias, float* __restrict__ Yf,
    short* __restrict__ Yb, int M, int base, float* xs)
{
    int rt = base >> 1, ct = base & 1;
    int t = threadIdx.x;
    int row_base = rt * 32;
    {
        int r = t >> 3, k0 = (t & 7) * 32;
        int row = row_base + r;
        if (row < M) {
            const float* xp = X + (size_t)row * 256 + k0;
            #pragma unroll
            for (int q = 0; q < 8; ++q) {
                float4 v = *(const float4*)(xp + q * 4);
                xs[(k0 + q * 4 + 0) * 36 + r] = v.x;
                xs[(k0 + q * 4 + 1) * 36 + r] = v.y;
                xs[(k0 + q * 4 + 2) * 36 + r] = v.z;
                xs[(k0 + q * 4 + 3) * 36 + r] = v.w;
            }
        } else {
            #pragma unroll
            for (int q = 0; q < 32; ++q) xs[(k0 + q) * 36 + r] = 0.f;
        }
    }
    __syncthreads();
    int c_base = ct * 128 + (t & 31) * 4;
    int r_base = (t >> 5) * 4;
    float acc[4][4];
    #pragma unroll
    for (int a = 0; a < 4; ++a)
        #pragma unroll
        for (int b = 0; b < 4; ++b) acc[a][b] = 0.f;
    for (int k = 0; k < 256; k += 4) {
        float w0[4], w1[4], w2[4], w3[4];
        { float4 v = *(const float4*)(W + (size_t)(c_base + 0) * 256 + k); LD4(w0, v); }
        { float4 v = *(const float4*)(W + (size_t)(c_base + 1) * 256 + k); LD4(w1, v); }
        { float4 v = *(const float4*)(W + (size_t)(c_base + 2) * 256 + k); LD4(w2, v); }
        { float4 v = *(const float4*)(W + (size_t)(c_base + 3) * 256 + k); LD4(w3, v); }
        #pragma unroll
        for (int kk = 0; kk < 4; ++kk) {
            float xl[4];
            float4 xv = *(const float4*)(&xs[(k + kk) * 36 + r_base]);
            LD4(xl, xv);
            #pragma unroll
            for (int ri = 0; ri < 4; ++ri) {
                acc[ri][0] += xl[ri] * w0[kk];
                acc[ri][1] += xl[ri] * w1[kk];
                acc[ri][2] += xl[ri] * w2[kk];
                acc[ri][3] += xl[ri] * w3[kk];
            }
        }
    }
    #pragma unroll
    for (int ri = 0; ri < 4; ++ri) {
        int row = row_base + r_base + ri;
        if (row < M) {
            float o0 = acc[ri][0] + (bias ? bias[c_base + 0] : 0.f);
            float o1 = acc[ri][1] + (bias ? bias[c_base + 1] : 0.f);
            float o2 = acc[ri][2] + (bias ? bias[c_base + 2] : 0.f);
            float o3 = acc[ri][3] + (bias ? bias[c_base + 3] : 0.f);
            if (Yb) {
                short4v o; o[0] = f2bf(o0); o[1] = f2bf(o1); o[2] = f2bf(o2); o[3] = f2bf(o3);
                *(short4v*)(Yb + (size_t)row * 256 + c_base) = o;
            } else {
                float4 o; o.x = o0; o.y = o1; o.z = o2; o.w = o3;
                *(float4*)(Yf + (size_t)row * 256 + c_base) = o;
            }
        }
    }
}

// ---------------- k_proj: 320 proj blocks + block 320 = {mask scan, wzp, Ah, Ch} ------------
__global__ void k_proj(const float* __restrict__ query, const float* __restrict__ key,
                       const float* __restrict__ value, const float* __restrict__ pos,
                       const float* __restrict__ Wq, const float* __restrict__ bq,
                       const float* __restrict__ Wk, const float* __restrict__ bk,
                       const float* __restrict__ Wv, const float* __restrict__ bv,
                       const float* __restrict__ Wp,
                       const float* __restrict__ ln_g, const float* __restrict__ ln_b,
                       const float* __restrict__ Wz, const int* __restrict__ mask,
                       float* __restrict__ qb, short* __restrict__ kbf,
                       short* __restrict__ vbf, short* __restrict__ pbf,
                       short* __restrict__ wzp, float* __restrict__ Ah, float* __restrict__ Ch,
                       int* __restrict__ idx, int* __restrict__ cnt)
{
    __shared__ float xs[256 * 36];
    int bx = blockIdx.x;
    if (bx == 320) {
        int lane = threadIdx.x & 63, wave = threadIdx.x >> 6;
        if (wave == 0) {
            for (int b = 0; b < 2; ++b) {
                int* idxb = idx + b * 512;
                #pragma unroll
                for (int q = 0; q < 8; ++q) idxb[q * 64 + lane] = -1;
                int total = 0;
                for (int q = 0; q < 8; ++q) {
                    int j = q * 64 + lane;
                    int u = (mask[b * 512 + j] == 0) ? 1 : 0;
                    unsigned long long bal = __ballot(u);
                    int p = total + __popcll(bal & ((1ull << lane) - 1ull));
                    if (u) idxb[p] = j;
                    total += (int)__popcll(bal);
                }
                if (total == 0) {
                    for (int q = 0; q < 8; ++q) idxb[q * 64 + lane] = q * 64 + lane;
                    total = 512;
                }
                if (lane == 0) cnt[b] = total;
            }
        } else if (wave == 1) {
            for (int id = lane; id < 2048; id += 64) {
                int m = id >> 9, rem = id & 511, l = rem >> 3, ii = rem & 7;
                int c = m * 32 + ((l >> 4) << 3) + ii, h = l & 15;
                wzp[id] = f2bf(ln_g[c] * Wz[c * 16 + h]);
            }
        } else if (wave == 2) {
            int h = lane & 15, part = lane >> 4;
            float a = 0.f, c = 0.f;
            #pragma unroll 4
            for (int cc = part * 32; cc < part * 32 + 32; ++cc) {
                float wv = Wz[cc * 16 + h];
                a += ln_g[cc] * wv;
                c += ln_b[cc] * wv;
            }
            a += __shfl_xor(a, 16); a += __shfl_xor(a, 32);
            c += __shfl_xor(c, 16); c += __shfl_xor(c, 32);
            if (part == 0) { Ah[h] = a; Ch[h] = c; }
        }
        return;
    }
    if (bx < 64)       proj_tile(query, Wq, bq, qb, nullptr, 1024, bx, xs);
    else if (bx < 128) proj_tile(key,   Wk, bk, nullptr, kbf, 1024, bx - 64, xs);
    else if (bx < 192) proj_tile(value, Wv, bv, nullptr, vbf, 1024, bx - 128, xs);
    else               proj_tile(pos,   Wp, nullptr, nullptr, pbf, 2046, bx - 192, xs);
}

// ---------------- k_compact: kbfC[b][jn][c] + vbTC[b][c][jn] from idx ----------------
__global__ void k_compact(const int* __restrict__ idx,
                          const short* __restrict__ kbf, const short* __restrict__ vbf,
                          short* __restrict__ kbfC, short* __restrict__ vbTC)
{
    __shared__ short st[32 * 264];
    const short8 z8v = {0,0,0,0,0,0,0,0};
    int bx = blockIdx.x;
    int b = bx >> 4, jn0 = (bx & 15) * 32;
    int t = threadIdx.x;
    int r = t >> 3, cc = (t & 7) * 32;
    int jn = jn0 + r;
    int jv = idx[b * 512 + jn];
    {
        short* dst = kbfC + ((size_t)b * 512 + jn) * 256 + cc;
        if (jv >= 0) {
            const short* src = kbf + ((size_t)b * 512 + jv) * 256 + cc;
            #pragma unroll
            for (int q = 0; q < 4; ++q) *(short8*)(dst + q * 8) = *(const short8*)(src + q * 8);
        } else {
            #pragma unroll
            for (int q = 0; q < 4; ++q) *(short8*)(dst + q * 8) = z8v;
        }
    }
    {
        if (jv >= 0) {
            const short* src = vbf + ((size_t)b * 512 + jv) * 256 + cc;
            #pragma unroll
            for (int q = 0; q < 4; ++q) *(short8*)(&st[r * 264 + cc + q * 8]) = *(const short8*)(src + q * 8);
        } else {
            #pragma unroll
            for (int q = 0; q < 4; ++q) *(short8*)(&st[r * 264 + cc + q * 8]) = z8v;
        }
        __syncthreads();
        int c = t;
        short tmp[32];
        #pragma unroll
        for (int q = 0; q < 32; ++q) tmp[q] = st[q * 264 + c];
        short* dst = vbTC + ((size_t)b * 256 + c) * 512 + jn0;
        #pragma unroll
        for (int q = 0; q < 4; ++q) *(short8*)(dst + q * 8) = *(const short8*)(&tmp[q * 8]);
    }
}

// ---------------- k_attn_z: R16 body + 1-deep z pipeline (256-VGPR budget, no spill) --------
__global__ void __launch_bounds__(256, 2) k_attn_z(
    const float* __restrict__ z,
    const float* __restrict__ qb, const short* __restrict__ kbfC, const short* __restrict__ pbf,
    const short* __restrict__ wzp, const float* __restrict__ Ah, const float* __restrict__ Ch,
    const float* __restrict__ u_bias, const float* __restrict__ v_bias,
    const int* __restrict__ idx, const int* __restrict__ cnt,
    const short* __restrict__ vbTC,
    const float* __restrict__ Wo, const float* __restrict__ bo, float* __restrict__ out)
{
    __shared__ __align__(16) char lds_raw[53248];
    float* scf    = (float*)lds_raw;                   // [512][17] f32 scores = 34816 B
    short* zs_all = (short*)(lds_raw + 34816);         // 4 waves x 2112 shorts = 16896 B
    short* wT     = (short*)(lds_raw + 34816);         // aliases zs_all (dead after main loop)
    float* redm   = (float*)(lds_raw + 51712);
    float* reds   = (float*)(lds_raw + 51968);
    float* ctxl   = (float*)(lds_raw + 52224);
    const short8 zero8 = {0, 0, 0, 0, 0, 0, 0, 0};

    int bi = blockIdx.x;
    int b = bi >> 9, i = bi & 511;
    int t = threadIdx.x;
    int lane = t & 63, wave = t >> 6;
    int h = lane & 15, g = lane >> 4;
    int l5 = lane >> 5, l31 = lane & 31;
    int np = (min(cnt[b], 512) + 31) & ~31;
    int nt16 = np >> 4;
    short* zs = zs_all + wave * 2112;
    const float* zb_ = z + (size_t)bi * 65536;

    short8 wz[4];
    #pragma unroll
    for (int m = 0; m < 4; ++m) wz[m] = *(const short8*)(wzp + m * 512 + lane * 8);
    float ah = Ah[h], ch = Ch[h];

    bool act = ((h & 1) == (g >> 1));
    int m_act = act ? (h >> 1) : 8;
    short8 qu8 = zero8, qv8 = zero8;
    {
        int c0q = h * 16 + (g & 1) * 8;
        const float* qp = qb + (size_t)bi * 256 + c0q;
        #pragma unroll
        for (int ii = 0; ii < 8; ++ii) {
            float qv_ = qp[ii];
            qu8[ii] = f2bf(0.25f * (qv_ + u_bias[c0q + ii]));
            qv8[ii] = f2bf(0.25f * (qv_ + v_bias[c0q + ii]));
        }
        if (!act) { qu8 = zero8; qv8 = zero8; }
    }

    // prefetch this wave's tile indices (per lane: idx of row h in tile q)
    int idxq[8];
    #pragma unroll
    for (int q = 0; q < 8; ++q) {
        int tl = wave + q * 4;
        idxq[q] = (tl < nt16) ? idx[b * 512 + tl * 16 + h] : -1;
    }

    // preload tile 0's z rows (coalesced: 2 rows x 512B per instr)
    float4 zv[8];
    if (wave < nt16) {
        #pragma unroll
        for (int m = 0; m < 8; ++m) {
            int r = 2 * m + l5;
            int jv = __shfl(idxq[0], r);
            int jr = (jv < 0) ? 0 : jv;
            zv[m] = *(const float4*)(zb_ + (size_t)jr * 128 + l31 * 4);
        }
    }

    float mloc = -3.0e38f;
    #pragma unroll
    for (int q = 0; q < 8; ++q) {
        int tl = wave + q * 4;
        if (tl < nt16) {                       // wave-uniform
            // 1) k/p score MFMAs (cover in-flight z loads of this tile)
            int jn = tl * 16 + h;
            int jvh = idxq[q];
            int jrp = 511 + ((jvh < 0) ? 0 : jvh) - i;
            const short* kr = kbfC + ((size_t)b * 512 + jn) * 256 + g * 8;
            const short* pr = pbf + ((size_t)b * 1023 + jrp) * 256 + g * 8;
            f32x4 acp = {0.f, 0.f, 0.f, 0.f};
            #pragma unroll
            for (int m = 0; m < 8; ++m) {
                short8 ka = *(const short8*)(kr + m * 32);
                short8 pa = *(const short8*)(pr + m * 32);
                short8 bu = (m == m_act) ? qu8 : zero8;
                short8 bv = (m == m_act) ? qv8 : zero8;
                acp = __builtin_amdgcn_mfma_f32_16x16x32_bf16(ka, bu, acp, 0, 0, 0);
                acp = __builtin_amdgcn_mfma_f32_16x16x32_bf16(pa, bv, acp, 0, 0, 0);
            }
            // 2) cvt z to bf16 -> wave-private LDS stage (zv dies here)
            #pragma unroll
            for (int m = 0; m < 8; ++m) {
                int r = 2 * m + l5;
                uint2 pk;
                pk.x = cvt_pk_bf16(zv[m].x, zv[m].y);
                pk.y = cvt_pk_bf16(zv[m].z, zv[m].w);
                *(uint2*)(&zs[r * 132 + l31 * 4]) = pk;
            }
            // 3) prefetch NEXT tile's z rows (hidden under stats+zMFMA+combine+next k/p)
            if (tl + 4 < nt16) {
                #pragma unroll
                for (int m = 0; m < 8; ++m) {
                    int r = 2 * m + l5;
                    int jv = __shfl(idxq[(q + 1) & 7], r);
                    int jr = (jv < 0) ? 0 : jv;
                    zv[m] = *(const float4*)(zb_ + (size_t)jr * 128 + l31 * 4);
                }
            }
            // 4) fragments + per-row stats (from bf16, error negligible)
            short8 af[4];
            float sum = 0.f, sq = 0.f;
            #pragma unroll
            for (int m = 0; m < 4; ++m) {
                short4v a0 = *(const short4v*)(&zs[h * 132 + g * 8 + m * 32]);
                short4v a1 = *(const short4v*)(&zs[h * 132 + g * 8 + m * 32 + 4]);
                short8 s8;
                s8[0] = a0[0]; s8[1] = a0[1]; s8[2] = a0[2]; s8[3] = a0[3];
                s8[4] = a1[0]; s8[5] = a1[1]; s8[6] = a1[2]; s8[7] = a1[3];
                af[m] = s8;
                #pragma unroll
                for (int ii = 0; ii < 8; ++ii) {
                    float x = bf2f(s8[ii]);
                    sum += x;
                    sq = fmaf(x, x, sq);
                }
            }
            sum += __shfl_xor(sum, 16); sum += __shfl_xor(sum, 32);
            sq  += __shfl_xor(sq, 16);  sq  += __shfl_xor(sq, 32);
            float mu = sum * (1.f / 128.f);
            float rs = rsqrtf(sq * (1.f / 128.f) - mu * mu + 1e-5f);
            // 5) z-bias MFMAs
            f32x4 accz = {0.f, 0.f, 0.f, 0.f};
            #pragma unroll
            for (int m = 0; m < 4; ++m)
                accz = __builtin_amdgcn_mfma_f32_16x16x32_bf16(af[m], wz[m], accz, 0, 0, 0);
            // 6) combine into score -> LDS (frees all score registers)
            #pragma unroll
            for (int reg = 0; reg < 4; ++reg) {
                int orow = g * 4 + reg;
                float mo = __shfl(mu, orow);
                float ro = __shfl(rs, orow);
                int jj = __shfl(idxq[q], orow);
                float s = acp[reg] + ro * (accz[reg] - mo * ah) + ch;
                s = (jj < 0) ? -3.0e38f : s;
                scf[(tl * 16 + orow) * 17 + h] = s;
                mloc = fmaxf(mloc, s);
            }
        }
    }

    // softmax over j (per head h)
    mloc = fmaxf(mloc, __shfl_xor(mloc, 16));
    mloc = fmaxf(mloc, __shfl_xor(mloc, 32));
    redm[wave * 16 + h] = mloc;
    __syncthreads();                           // all waves done with main loop + zs
    float mg = fmaxf(fmaxf(redm[h], redm[16 + h]), fmaxf(redm[32 + h], redm[48 + h]));
    float ssum = 0.f;
    for (int q = 0; q < 8; ++q) {
        int tl = wave + q * 4;
        if (tl < nt16) {
            #pragma unroll
            for (int reg = 0; reg < 4; ++reg) {
                int j = tl * 16 + g * 4 + reg;
                float e = __expf(scf[j * 17 + h] - mg);
                ssum += e;
                scf[j * 17 + h] = e;
            }
        }
    }
    ssum += __shfl_xor(ssum, 16); ssum += __shfl_xor(ssum, 32);
    reds[wave * 16 + h] = ssum;
    __syncthreads();
    float sg = reds[h] + reds[16 + h] + reds[32 + h] + reds[48 + h];
    float inv = 1.f / sg;
    for (int q = 0; q < 8; ++q) {
        int tl = wave + q * 4;
        if (tl < nt16) {
            short4v w4;
            #pragma unroll
            for (int reg = 0; reg < 4; ++reg)
                w4[reg] = f2bf(scf[(tl * 16 + g * 4 + reg) * 17 + h] * inv);
            *(short4v*)(&wT[h * 520 + tl * 16 + g * 4]) = w4;
        }
    }
    __syncthreads();

    // ctx via MFMA over compacted j
    #pragma unroll
    for (int q = 0; q < 4; ++q) {
        int hp = wave * 4 + q;
        int c0 = hp * 16;
        const short* vrow = vbTC + ((size_t)b * 256 + c0 + h) * 512;
        f32x4 a0 = {0.f, 0.f, 0.f, 0.f};
        for (int jn0 = 0; jn0 < np; jn0 += 32) {
            short8 wA = *(const short8*)(&wT[hp * 520 + jn0 + g * 8]);
            short8 vB = *(const short8*)(vrow + jn0 + g * 8);
            a0 = __builtin_amdgcn_mfma_f32_16x16x32_bf16(wA, vB, a0, 0, 0, 0);
        }
        if (g == 0) ctxl[c0 + h] = a0[0];
    }
    __syncthreads();

    // fused output projection: thread t -> out channel t (Wo row L2-hot)
    {
        float acc = bo[t];
        const float* wrow = Wo + (size_t)t * 256;
        #pragma unroll 4
        for (int k = 0; k < 256; k += 8) {
            float4 w0 = *(const float4*)(wrow + k);
            float4 w1 = *(const float4*)(wrow + k + 4);
            acc += ctxl[k + 0] * w0.x + ctxl[k + 1] * w0.y
                 + ctxl[k + 2] * w0.z + ctxl[k + 3] * w0.w
                 + ctxl[k + 4] * w1.x + ctxl[k + 5] * w1.y
                 + ctxl[k + 6] * w1.z + ctxl[k + 7] * w1.w;
        }
        out[(size_t)bi * 256 + t] = acc;
    }
}

extern "C" void kernel_launch(void* const* d_in, const int* in_sizes, int n_in,
                              void* d_out, int out_size, void* d_ws, size_t ws_size,
                              hipStream_t stream) {
    const float* query = (const float*)d_in[0];
    const float* key   = (const float*)d_in[1];
    const float* value = (const float*)d_in[2];
    const float* pos   = (const float*)d_in[3];
    const float* z     = (const float*)d_in[4];
    const int*   mask  = (const int*)d_in[5];
    const float* Wq = (const float*)d_in[6];
    const float* bq = (const float*)d_in[7];
    const float* Wk = (const float*)d_in[8];
    const float* bk = (const float*)d_in[9];
    const float* Wv = (const float*)d_in[10];
    const float* bv = (const float*)d_in[11];
    const float* Wp = (const float*)d_in[12];
    const float* u_bias = (const float*)d_in[13];
    const float* v_bias = (const float*)d_in[14];
    const float* Wo = (const float*)d_in[15];
    const float* bo = (const float*)d_in[16];
    const float* ln_g = (const float*)d_in[17];
    const float* ln_b = (const float*)d_in[18];
    const float* Wz = (const float*)d_in[19];

    char* ws = (char*)d_ws;
    float* qb   = (float*)(ws + 0);                     // 1 MB
    short* kbf  = (short*)(ws + (1u << 20));            // 512 KB
    short* vbf  = (short*)(ws + 1572864u);              // 512 KB
    short* pbf  = (short*)(ws + (2u << 20));            // 1 MB
    short* wzp  = (short*)(ws + (3u << 20));            // 4 KB
    float* Ah   = (float*)(ws + (3u << 20) + 4096);
    float* Ch   = (float*)(ws + (3u << 20) + 4160);
    int*   idx  = (int*)(ws + (3u << 20) + 8192);       // 4 KB
    int*   cnt  = (int*)(ws + (3u << 20) + 16384);
    short* kbfC = (short*)(ws + (4u << 20));            // 512 KB
    short* vbTC = (short*)(ws + 4718592u);              // 512 KB

    hipLaunchKernelGGL(k_proj, dim3(321), dim3(256), 0, stream,
                       query, key, value, pos, Wq, bq, Wk, bk, Wv, bv, Wp,
                       ln_g, ln_b, Wz, mask,
                       qb, kbf, vbf, pbf, wzp, Ah, Ch, idx, cnt);
    hipLaunchKernelGGL(k_compact, dim3(32), dim3(256), 0, stream,
                       idx, kbf, vbf, kbfC, vbTC);
    hipLaunchKernelGGL(k_attn_z, dim3(1024), dim3(256), 0, stream,
                       z, qb, kbfC, pbf, wzp, Ah, Ch, u_bias, v_bias, idx, cnt, vbTC,
                       Wo, bo, (float*)d_out);
}

// Round 18
// 154.617 us; speedup vs baseline: 1.0151x; 1.0151x over previous
//
#include <hip/hip_runtime.h>
#include <hip/hip_bf16.h>

typedef __attribute__((ext_vector_type(8))) short short8;
typedef __attribute__((ext_vector_type(4))) short short4v;
typedef __attribute__((ext_vector_type(4))) float f32x4;

#define LD4(dst, v4) { dst[0]=(v4).x; dst[1]=(v4).y; dst[2]=(v4).z; dst[3]=(v4).w; }

// B=2, T=512, CM=256, CZ=128, H=16, DH=16
static __device__ __forceinline__ short f2bf(float f) {
    union { float f; unsigned u; } v; v.f = f;
    unsigned r = (v.u + 0x7FFFu + ((v.u >> 16) & 1u)) >> 16;
    return (short)r;
}
static __device__ __forceinline__ float bf2f(short s) {
    union { unsigned u; float f; } v; v.u = ((unsigned)(unsigned short)s) << 16;
    return v.f;
}
static __device__ __forceinline__ unsigned cvt_pk_bf16(float lo, float hi) {
    unsigned r;
    asm volatile("v_cvt_pk_bf16_f32 %0, %1, %2" : "=v"(r) : "v"(lo), "v"(hi));
    return r;
}

// ---------------- proj tile (32 rows x 128 cols), R5/R7-proven ----------------
static __device__ __forceinline__ void proj_tile(
    const float* __restrict__ X, const float* __restrict__ W,
    const float* __restrict__ bias, float* __restrict__ Yf,
    short* __restrict__ Yb, int M, int base, float* xs)
{
    int rt = base >> 1, ct = base & 1;
    int t = threadIdx.x;
    int row_base = rt * 32;
    {
        int r = t >> 3, k0 = (t & 7) * 32;
        int row = row_base + r;
        if (row < M) {
            const float* xp = X + (size_t)row * 256 + k0;
            #pragma unroll
            for (int q = 0; q < 8; ++q) {
                float4 v = *(const float4*)(xp + q * 4);
                xs[(k0 + q * 4 + 0) * 36 + r] = v.x;
                xs[(k0 + q * 4 + 1) * 36 + r] = v.y;
                xs[(k0 + q * 4 + 2) * 36 + r] = v.z;
                xs[(k0 + q * 4 + 3) * 36 + r] = v.w;
            }
        } else {
            #pragma unroll
            for (int q = 0; q < 32; ++q) xs[(k0 + q) * 36 + r] = 0.f;
        }
    }
    __syncthreads();
    int c_base = ct * 128 + (t & 31) * 4;
    int r_base = (t >> 5) * 4;
    float acc[4][4];
    #pragma unroll
    for (int a = 0; a < 4; ++a)
        #pragma unroll
        for (int b = 0; b < 4; ++b) acc[a][b] = 0.f;
    for (int k = 0; k < 256; k += 4) {
        float w0[4], w1[4], w2[4], w3[4];
        { float4 v = *(const float4*)(W + (size_t)(c_base + 0) * 256 + k); LD4(w0, v); }
        { float4 v = *(const float4*)(W + (size_t)(c_base + 1) * 256 + k); LD4(w1, v); }
        { float4 v = *(const float4*)(W + (size_t)(c_base + 2) * 256 + k); LD4(w2, v); }
        { float4 v = *(const float4*)(W + (size_t)(c_base + 3) * 256 + k); LD4(w3, v); }
        #pragma unroll
        for (int kk = 0; kk < 4; ++kk) {
            float xl[4];
            float4 xv = *(const float4*)(&xs[(k + kk) * 36 + r_base]);
            LD4(xl, xv);
            #pragma unroll
            for (int ri = 0; ri < 4; ++ri) {
                acc[ri][0] += xl[ri] * w0[kk];
                acc[ri][1] += xl[ri] * w1[kk];
                acc[ri][2] += xl[ri] * w2[kk];
                acc[ri][3] += xl[ri] * w3[kk];
            }
        }
    }
    #pragma unroll
    for (int ri = 0; ri < 4; ++ri) {
        int row = row_base + r_base + ri;
        if (row < M) {
            float o0 = acc[ri][0] + (bias ? bias[c_base + 0] : 0.f);
            float o1 = acc[ri][1] + (bias ? bias[c_base + 1] : 0.f);
            float o2 = acc[ri][2] + (bias ? bias[c_base + 2] : 0.f);
            float o3 = acc[ri][3] + (bias ? bias[c_base + 3] : 0.f);
            if (Yb) {
                short4v o; o[0] = f2bf(o0); o[1] = f2bf(o1); o[2] = f2bf(o2); o[3] = f2bf(o3);
                *(short4v*)(Yb + (size_t)row * 256 + c_base) = o;
            } else {
                float4 o; o.x = o0; o.y = o1; o.z = o2; o.w = o3;
                *(float4*)(Yf + (size_t)row * 256 + c_base) = o;
            }
        }
    }
}

// ---------------- k_proj: 320 proj blocks + block 320 = {mask scan, wzp, Ah, Ch} ------------
__global__ void k_proj(const float* __restrict__ query, const float* __restrict__ key,
                       const float* __restrict__ value, const float* __restrict__ pos,
                       const float* __restrict__ Wq, const float* __restrict__ bq,
                       const float* __restrict__ Wk, const float* __restrict__ bk,
                       const float* __restrict__ Wv, const float* __restrict__ bv,
                       const float* __restrict__ Wp,
                       const float* __restrict__ ln_g, const float* __restrict__ ln_b,
                       const float* __restrict__ Wz, const int* __restrict__ mask,
                       float* __restrict__ qb, short* __restrict__ kbf,
                       short* __restrict__ vbf, short* __restrict__ pbf,
                       short* __restrict__ wzp, float* __restrict__ Ah, float* __restrict__ Ch,
                       int* __restrict__ idx, int* __restrict__ cnt)
{
    __shared__ float xs[256 * 36];
    int bx = blockIdx.x;
    if (bx == 320) {
        int lane = threadIdx.x & 63, wave = threadIdx.x >> 6;
        if (wave == 0) {
            for (int b = 0; b < 2; ++b) {
                int* idxb = idx + b * 512;
                #pragma unroll
                for (int q = 0; q < 8; ++q) idxb[q * 64 + lane] = -1;
                int total = 0;
                for (int q = 0; q < 8; ++q) {
                    int j = q * 64 + lane;
                    int u = (mask[b * 512 + j] == 0) ? 1 : 0;
                    unsigned long long bal = __ballot(u);
                    int p = total + __popcll(bal & ((1ull << lane) - 1ull));
                    if (u) idxb[p] = j;
                    total += (int)__popcll(bal);
                }
                if (total == 0) {
                    for (int q = 0; q < 8; ++q) idxb[q * 64 + lane] = q * 64 + lane;
                    total = 512;
                }
                if (lane == 0) cnt[b] = total;
            }
        } else if (wave == 1) {
            for (int id = lane; id < 2048; id += 64) {
                int m = id >> 9, rem = id & 511, l = rem >> 3, ii = rem & 7;
                int c = m * 32 + ((l >> 4) << 3) + ii, h = l & 15;
                wzp[id] = f2bf(ln_g[c] * Wz[c * 16 + h]);
            }
        } else if (wave == 2) {
            int h = lane & 15, part = lane >> 4;
            float a = 0.f, c = 0.f;
            #pragma unroll 4
            for (int cc = part * 32; cc < part * 32 + 32; ++cc) {
                float wv = Wz[cc * 16 + h];
                a += ln_g[cc] * wv;
                c += ln_b[cc] * wv;
            }
            a += __shfl_xor(a, 16); a += __shfl_xor(a, 32);
            c += __shfl_xor(c, 16); c += __shfl_xor(c, 32);
            if (part == 0) { Ah[h] = a; Ch[h] = c; }
        }
        return;
    }
    if (bx < 64)       proj_tile(query, Wq, bq, qb, nullptr, 1024, bx, xs);
    else if (bx < 128) proj_tile(key,   Wk, bk, nullptr, kbf, 1024, bx - 64, xs);
    else if (bx < 192) proj_tile(value, Wv, bv, nullptr, vbf, 1024, bx - 128, xs);
    else               proj_tile(pos,   Wp, nullptr, nullptr, pbf, 2046, bx - 192, xs);
}

// ---------------- k_compact: kbfC[b][jn][c] + vbTC[b][c][jn] from idx ----------------
__global__ void k_compact(const int* __restrict__ idx,
                          const short* __restrict__ kbf, const short* __restrict__ vbf,
                          short* __restrict__ kbfC, short* __restrict__ vbTC)
{
    __shared__ short st[32 * 264];
    const short8 z8v = {0,0,0,0,0,0,0,0};
    int bx = blockIdx.x;
    int b = bx >> 4, jn0 = (bx & 15) * 32;
    int t = threadIdx.x;
    int r = t >> 3, cc = (t & 7) * 32;
    int jn = jn0 + r;
    int jv = idx[b * 512 + jn];
    {
        short* dst = kbfC + ((size_t)b * 512 + jn) * 256 + cc;
        if (jv >= 0) {
            const short* src = kbf + ((size_t)b * 512 + jv) * 256 + cc;
            #pragma unroll
            for (int q = 0; q < 4; ++q) *(short8*)(dst + q * 8) = *(const short8*)(src + q * 8);
        } else {
            #pragma unroll
            for (int q = 0; q < 4; ++q) *(short8*)(dst + q * 8) = z8v;
        }
    }
    {
        if (jv >= 0) {
            const short* src = vbf + ((size_t)b * 512 + jv) * 256 + cc;
            #pragma unroll
            for (int q = 0; q < 4; ++q) *(short8*)(&st[r * 264 + cc + q * 8]) = *(const short8*)(src + q * 8);
        } else {
            #pragma unroll
            for (int q = 0; q < 4; ++q) *(short8*)(&st[r * 264 + cc + q * 8]) = z8v;
        }
        __syncthreads();
        int c = t;
        short tmp[32];
        #pragma unroll
        for (int q = 0; q < 32; ++q) tmp[q] = st[q * 264 + c];
        short* dst = vbTC + ((size_t)b * 256 + c) * 512 + jn0;
        #pragma unroll
        for (int q = 0; q < 4; ++q) *(short8*)(dst + q * 8) = *(const short8*)(&tmp[q * 8]);
    }
}

// ---------------- k_attn_z: scores-in-LDS body + relaxed launch_bounds (R16, best) ----------
__global__ void __launch_bounds__(256, 2) k_attn_z(
    const float* __restrict__ z,
    const float* __restrict__ qb, const short* __restrict__ kbfC, const short* __restrict__ pbf,
    const short* __restrict__ wzp, const float* __restrict__ Ah, const float* __restrict__ Ch,
    const float* __restrict__ u_bias, const float* __restrict__ v_bias,
    const int* __restrict__ idx, const int* __restrict__ cnt,
    const short* __restrict__ vbTC,
    const float* __restrict__ Wo, const float* __restrict__ bo, float* __restrict__ out)
{
    __shared__ __align__(16) char lds_raw[53248];
    float* scf    = (float*)lds_raw;                   // [512][17] f32 scores = 34816 B
    short* zs_all = (short*)(lds_raw + 34816);         // 4 waves x 2112 shorts = 16896 B
    short* wT     = (short*)(lds_raw + 34816);         // aliases zs_all (dead after main loop)
    float* redm   = (float*)(lds_raw + 51712);
    float* reds   = (float*)(lds_raw + 51968);
    float* ctxl   = (float*)(lds_raw + 52224);
    const short8 zero8 = {0, 0, 0, 0, 0, 0, 0, 0};

    int bi = blockIdx.x;
    int b = bi >> 9, i = bi & 511;
    int t = threadIdx.x;
    int lane = t & 63, wave = t >> 6;
    int h = lane & 15, g = lane >> 4;
    int l5 = lane >> 5, l31 = lane & 31;
    int np = (min(cnt[b], 512) + 31) & ~31;
    int nt16 = np >> 4;
    short* zs = zs_all + wave * 2112;
    const float* zb_ = z + (size_t)bi * 65536;

    short8 wz[4];
    #pragma unroll
    for (int m = 0; m < 4; ++m) wz[m] = *(const short8*)(wzp + m * 512 + lane * 8);
    float ah = Ah[h], ch = Ch[h];

    bool act = ((h & 1) == (g >> 1));
    int m_act = act ? (h >> 1) : 8;
    short8 qu8 = zero8, qv8 = zero8;
    {
        int c0q = h * 16 + (g & 1) * 8;
        const float* qp = qb + (size_t)bi * 256 + c0q;
        #pragma unroll
        for (int ii = 0; ii < 8; ++ii) {
            float qv_ = qp[ii];
            qu8[ii] = f2bf(0.25f * (qv_ + u_bias[c0q + ii]));
            qv8[ii] = f2bf(0.25f * (qv_ + v_bias[c0q + ii]));
        }
        if (!act) { qu8 = zero8; qv8 = zero8; }
    }

    // prefetch this wave's tile indices (per lane: idx of row h in tile q)
    int idxq[8];
    #pragma unroll
    for (int q = 0; q < 8; ++q) {
        int tl = wave + q * 4;
        idxq[q] = (tl < nt16) ? idx[b * 512 + tl * 16 + h] : -1;
    }

    float mloc = -3.0e38f;
    #pragma unroll
    for (int q = 0; q < 8; ++q) {
        int tl = wave + q * 4;
        if (tl < nt16) {                       // wave-uniform
            // 1) issue coalesced z loads (2 rows x 512B per instr)
            float4 zv[8];
            #pragma unroll
            for (int m = 0; m < 8; ++m) {
                int r = 2 * m + l5;
                int jv = __shfl(idxq[q], r);
                int jr = (jv < 0) ? 0 : jv;
                zv[m] = *(const float4*)(zb_ + (size_t)jr * 128 + l31 * 4);
            }
            // 2) k/p score MFMAs (hide z-load latency)
            int jn = tl * 16 + h;
            int jvh = idxq[q];
            int jrp = 511 + ((jvh < 0) ? 0 : jvh) - i;
            const short* kr = kbfC + ((size_t)b * 512 + jn) * 256 + g * 8;
            const short* pr = pbf + ((size_t)b * 1023 + jrp) * 256 + g * 8;
            f32x4 acp = {0.f, 0.f, 0.f, 0.f};
            #pragma unroll
            for (int m = 0; m < 8; ++m) {
                short8 ka = *(const short8*)(kr + m * 32);
                short8 pa = *(const short8*)(pr + m * 32);
                short8 bu = (m == m_act) ? qu8 : zero8;
                short8 bv = (m == m_act) ? qv8 : zero8;
                acp = __builtin_amdgcn_mfma_f32_16x16x32_bf16(ka, bu, acp, 0, 0, 0);
                acp = __builtin_amdgcn_mfma_f32_16x16x32_bf16(pa, bv, acp, 0, 0, 0);
            }
            // 3) cvt z to bf16 -> wave-private LDS stage (zv dies here)
            #pragma unroll
            for (int m = 0; m < 8; ++m) {
                int r = 2 * m + l5;
                uint2 pk;
                pk.x = cvt_pk_bf16(zv[m].x, zv[m].y);
                pk.y = cvt_pk_bf16(zv[m].z, zv[m].w);
                *(uint2*)(&zs[r * 132 + l31 * 4]) = pk;
            }
            // 4) fragments + per-row stats (from bf16, error negligible)
            short8 af[4];
            float sum = 0.f, sq = 0.f;
            #pragma unroll
            for (int m = 0; m < 4; ++m) {
                short4v a0 = *(const short4v*)(&zs[h * 132 + g * 8 + m * 32]);
                short4v a1 = *(const short4v*)(&zs[h * 132 + g * 8 + m * 32 + 4]);
                short8 s8;
                s8[0] = a0[0]; s8[1] = a0[1]; s8[2] = a0[2]; s8[3] = a0[3];
                s8[4] = a1[0]; s8[5] = a1[1]; s8[6] = a1[2]; s8[7] = a1[3];
                af[m] = s8;
                #pragma unroll
                for (int ii = 0; ii < 8; ++ii) {
                    float x = bf2f(s8[ii]);
                    sum += x;
                    sq = fmaf(x, x, sq);
                }
            }
            sum += __shfl_xor(sum, 16); sum += __shfl_xor(sum, 32);
            sq  += __shfl_xor(sq, 16);  sq  += __shfl_xor(sq, 32);
            float mu = sum * (1.f / 128.f);
            float rs = rsqrtf(sq * (1.f / 128.f) - mu * mu + 1e-5f);
            // 5) z-bias MFMAs
            f32x4 accz = {0.f, 0.f, 0.f, 0.f};
            #pragma unroll
            for (int m = 0; m < 4; ++m)
                accz = __builtin_amdgcn_mfma_f32_16x16x32_bf16(af[m], wz[m], accz, 0, 0, 0);
            // 6) combine into score -> LDS (frees all score registers)
            #pragma unroll
            for (int reg = 0; reg < 4; ++reg) {
                int orow = g * 4 + reg;
                float mo = __shfl(mu, orow);
                float ro = __shfl(rs, orow);
                int jj = __shfl(idxq[q], orow);
                float s = acp[reg] + ro * (accz[reg] - mo * ah) + ch;
                s = (jj < 0) ? -3.0e38f : s;
                scf[(tl * 16 + orow) * 17 + h] = s;
                mloc = fmaxf(mloc, s);
            }
        }
    }

    // softmax over j (per head h)
    mloc = fmaxf(mloc, __shfl_xor(mloc, 16));
    mloc = fmaxf(mloc, __shfl_xor(mloc, 32));
    redm[wave * 16 + h] = mloc;
    __syncthreads();                           // all waves done with main loop + zs
    float mg = fmaxf(fmaxf(redm[h], redm[16 + h]), fmaxf(redm[32 + h], redm[48 + h]));
    float ssum = 0.f;
    for (int q = 0; q < 8; ++q) {
        int tl = wave + q * 4;
        if (tl < nt16) {
            #pragma unroll
            for (int reg = 0; reg < 4; ++reg) {
                int j = tl * 16 + g * 4 + reg;
                float e = __expf(scf[j * 17 + h] - mg);
                ssum += e;
                scf[j * 17 + h] = e;
            }
        }
    }
    ssum += __shfl_xor(ssum, 16); ssum += __shfl_xor(ssum, 32);
    reds[wave * 16 + h] = ssum;
    __syncthreads();
    float sg = reds[h] + reds[16 + h] + reds[32 + h] + reds[48 + h];
    float inv = 1.f / sg;
    for (int q = 0; q < 8; ++q) {
        int tl = wave + q * 4;
        if (tl < nt16) {
            short4v w4;
            #pragma unroll
            for (int reg = 0; reg < 4; ++reg)
                w4[reg] = f2bf(scf[(tl * 16 + g * 4 + reg) * 17 + h] * inv);
            *(short4v*)(&wT[h * 520 + tl * 16 + g * 4]) = w4;
        }
    }
    __syncthreads();

    // ctx via MFMA over compacted j
    #pragma unroll
    for (int q = 0; q < 4; ++q) {
        int hp = wave * 4 + q;
        int c0 = hp * 16;
        const short* vrow = vbTC + ((size_t)b * 256 + c0 + h) * 512;
        f32x4 a0 = {0.f, 0.f, 0.f, 0.f};
        for (int jn0 = 0; jn0 < np; jn0 += 32) {
            short8 wA = *(const short8*)(&wT[hp * 520 + jn0 + g * 8]);
            short8 vB = *(const short8*)(vrow + jn0 + g * 8);
            a0 = __builtin_amdgcn_mfma_f32_16x16x32_bf16(wA, vB, a0, 0, 0, 0);
        }
        if (g == 0) ctxl[c0 + h] = a0[0];
    }
    __syncthreads();

    // fused output projection: thread t -> out channel t (Wo row L2-hot)
    {
        float acc = bo[t];
        const float* wrow = Wo + (size_t)t * 256;
        #pragma unroll 4
        for (int k = 0; k < 256; k += 8) {
            float4 w0 = *(const float4*)(wrow + k);
            float4 w1 = *(const float4*)(wrow + k + 4);
            acc += ctxl[k + 0] * w0.x + ctxl[k + 1] * w0.y
                 + ctxl[k + 2] * w0.z + ctxl[k + 3] * w0.w
                 + ctxl[k + 4] * w1.x + ctxl[k + 5] * w1.y
                 + ctxl[k + 6] * w1.z + ctxl[k + 7] * w1.w;
        }
        out[(size_t)bi * 256 + t] = acc;
    }
}

extern "C" void kernel_launch(void* const* d_in, const int* in_sizes, int n_in,
                              void* d_out, int out_size, void* d_ws, size_t ws_size,
                              hipStream_t stream) {
    const float* query = (const float*)d_in[0];
    const float* key   = (const float*)d_in[1];
    const float* value = (const float*)d_in[2];
    const float* pos   = (const float*)d_in[3];
    const float* z     = (const float*)d_in[4];
    const int*   mask  = (const int*)d_in[5];
    const float* Wq = (const float*)d_in[6];
    const float* bq = (const float*)d_in[7];
    const float* Wk = (const float*)d_in[8];
    const float* bk = (const float*)d_in[9];
    const float* Wv = (const float*)d_in[10];
    const float* bv = (const float*)d_in[11];
    const float* Wp = (const float*)d_in[12];
    const float* u_bias = (const float*)d_in[13];
    const float* v_bias = (const float*)d_in[14];
    const float* Wo = (const float*)d_in[15];
    const float* bo = (const float*)d_in[16];
    const float* ln_g = (const float*)d_in[17];
    const float* ln_b = (const float*)d_in[18];
    const float* Wz = (const float*)d_in[19];

    char* ws = (char*)d_ws;
    float* qb   = (float*)(ws + 0);                     // 1 MB
    short* kbf  = (short*)(ws + (1u << 20));            // 512 KB
    short* vbf  = (short*)(ws + 1572864u);              // 512 KB
    short* pbf  = (short*)(ws + (2u << 20));            // 1 MB
    short* wzp  = (short*)(ws + (3u << 20));            // 4 KB
    float* Ah   = (float*)(ws + (3u << 20) + 4096);
    float* Ch   = (float*)(ws + (3u << 20) + 4160);
    int*   idx  = (int*)(ws + (3u << 20) + 8192);       // 4 KB
    int*   cnt  = (int*)(ws + (3u << 20) + 16384);
    short* kbfC = (short*)(ws + (4u << 20));            // 512 KB
    short* vbTC = (short*)(ws + 4718592u);              // 512 KB

    hipLaunchKernelGGL(k_proj, dim3(321), dim3(256), 0, stream,
                       query, key, value, pos, Wq, bq, Wk, bk, Wv, bv, Wp,
                       ln_g, ln_b, Wz, mask,
                       qb, kbf, vbf, pbf, wzp, Ah, Ch, idx, cnt);
    hipLaunchKernelGGL(k_compact, dim3(32), dim3(256), 0, stream,
                       idx, kbf, vbf, kbfC, vbTC);
    hipLaunchKernelGGL(k_attn_z, dim3(1024), dim3(256), 0, stream,
                       z, qb, kbfC, pbf, wzp, Ah, Ch, u_bias, v_bias, idx, cnt, vbTC,
                       Wo, bo, (float*)d_out);
}